// Round 1
// baseline (236.934 us; speedup 1.0000x reference)
//
#include <hip/hip_runtime.h>
#include <hip/hip_bf16.h>

typedef __bf16 bf16x8 __attribute__((ext_vector_type(8)));
typedef float f32x4 __attribute__((ext_vector_type(4)));

#define MFMA16(a, b, c) __builtin_amdgcn_mfma_f32_16x16x32_bf16(a, b, c, 0, 0, 0)

static constexpr int NSP = 4096;   // H*W
static constexpr float SCALE = 0.25f;
static constexpr float L2E = 1.4426950408889634f;

__device__ __forceinline__ bf16x8 ld_frag_g(const __bf16* p) {
  int4 v = *(const int4*)p;
  return __builtin_bit_cast(bf16x8, v);
}

// ---------------- K0: weight prep (fp32 -> bf16, fold SCALE into Wq/bq) ----
__global__ void k_prep(const float* __restrict__ Wq, const float* __restrict__ bq,
                       const float* __restrict__ Wk, const float* __restrict__ Wv,
                       const float* __restrict__ Wo,
                       __bf16* __restrict__ wqb, __bf16* __restrict__ wkb,
                       __bf16* __restrict__ wvb, __bf16* __restrict__ wob,
                       float* __restrict__ bqs) {
  int i = blockIdx.x * 256 + threadIdx.x;
  if (i < 16384)      wqb[i]          = (__bf16)(Wq[i] * SCALE);
  else if (i < 49152) wkb[i - 16384]  = (__bf16)Wk[i - 16384];
  else if (i < 81920) wvb[i - 49152]  = (__bf16)Wv[i - 49152];
  else if (i < 98304) wob[i - 81920]  = (__bf16)Wo[i - 81920];
  if (i < 128) bqs[i] = bq[i] * SCALE;
}

// Per-wave: write D[o][n] fragments (o rows, 16 n cols) transposed into a
// [16 n][128 o] bf16 LDS tile (XOR swizzled), then copy rows coalesced to dst.
// dst_base points at the first of 16 consecutive rows (row stride = 128 elems).
__device__ __forceinline__ void store_tile_T(char* myt, const f32x4* acc, int g, int r,
                                             __bf16* dst_base) {
#pragma unroll
  for (int oc = 0; oc < 8; ++oc) {
#pragma unroll
    for (int rr = 0; rr < 4; ++rr) {
      int o = oc * 16 + g * 4 + rr;
      int byte = (r << 8) + (o << 1);
      byte ^= (r & 7) << 4;
      *(__bf16*)(myt + byte) = (__bf16)acc[oc][rr];
    }
  }
  int l = g * 16 + r;
#pragma unroll
  for (int p = 0; p < 4; ++p) {
    int u = p * 64 + l, row = u >> 4, seg = u & 15;
    int byte = (row << 8) + (seg << 4);
    byte ^= (row & 7) << 4;
    int4 v = *(int4*)(myt + byte);
    *(int4*)(dst_base + row * 128 + seg * 8) = v;
  }
}

// ---------------- K1: Q projection -> Qt [B][N][128] bf16 (scaled) ---------
__global__ __launch_bounds__(256) void k_qproj(const float* __restrict__ xq,
                                               const __bf16* __restrict__ wqb,
                                               const float* __restrict__ bqs,
                                               __bf16* __restrict__ Qt) {
  const int b = blockIdx.x >> 6;
  const int n0 = (blockIdx.x & 63) << 6;
  const int t = threadIdx.x, w = t >> 6, l = t & 63, r = l & 15, g = l >> 4;
  const int nl = n0 + (w << 4) + r;
  __shared__ __align__(16) char lds[16384];
  char* myt = lds + (w << 12);

  const float* xb = xq + ((size_t)b << 19);  // b*128*4096
  bf16x8 bx[4];
#pragma unroll
  for (int cc = 0; cc < 4; ++cc) {
#pragma unroll
    for (int i = 0; i < 8; ++i) {
      int c = cc * 32 + g * 8 + i;
      bx[cc][i] = (__bf16)xb[c * 4096 + nl];
    }
  }
  f32x4 acc[8];
#pragma unroll
  for (int oc = 0; oc < 8; ++oc)
#pragma unroll
    for (int rr = 0; rr < 4; ++rr) acc[oc][rr] = bqs[oc * 16 + g * 4 + rr];
#pragma unroll
  for (int oc = 0; oc < 8; ++oc) {
#pragma unroll
    for (int cc = 0; cc < 4; ++cc) {
      bf16x8 a = ld_frag_g(wqb + (oc * 16 + r) * 128 + cc * 32 + g * 8);
      acc[oc] = MFMA16(a, bx[cc], acc[oc]);
    }
  }
  store_tile_T(myt, acc, g, r, Qt + ((size_t)(b * NSP + n0 + w * 16)) * 128);
}

// ---------------- K2: K,V projection -> Kt [B][N][128], V [B][128][N] ------
__global__ __launch_bounds__(256) void k_kvproj(const float* __restrict__ xkv,
                                                const __bf16* __restrict__ wkb,
                                                const __bf16* __restrict__ wvb,
                                                const float* __restrict__ bk,
                                                const float* __restrict__ bv,
                                                __bf16* __restrict__ Kt,
                                                __bf16* __restrict__ Vm) {
  const int b = blockIdx.x >> 6;
  const int n0 = (blockIdx.x & 63) << 6;
  const int t = threadIdx.x, w = t >> 6, l = t & 63, r = l & 15, g = l >> 4;
  const int nl = n0 + (w << 4) + r;
  __shared__ __align__(16) char lds[16384];
  char* myt = lds + (w << 12);

  const float* xb = xkv + ((size_t)b << 20);  // b*256*4096
  bf16x8 bx[8];
#pragma unroll
  for (int cc = 0; cc < 8; ++cc) {
#pragma unroll
    for (int i = 0; i < 8; ++i) {
      int c = cc * 32 + g * 8 + i;
      bx[cc][i] = (__bf16)xb[(size_t)c * 4096 + nl];
    }
  }
  // K part
  f32x4 acc[8];
#pragma unroll
  for (int oc = 0; oc < 8; ++oc)
#pragma unroll
    for (int rr = 0; rr < 4; ++rr) acc[oc][rr] = bk[oc * 16 + g * 4 + rr];
#pragma unroll
  for (int oc = 0; oc < 8; ++oc) {
#pragma unroll
    for (int cc = 0; cc < 8; ++cc) {
      bf16x8 a = ld_frag_g(wkb + (oc * 16 + r) * 256 + cc * 32 + g * 8);
      acc[oc] = MFMA16(a, bx[cc], acc[oc]);
    }
  }
  store_tile_T(myt, acc, g, r, Kt + ((size_t)(b * NSP + n0 + w * 16)) * 128);
  // V part (direct store, layout [c][n] so col writes are lane-contiguous)
  f32x4 av[8];
#pragma unroll
  for (int oc = 0; oc < 8; ++oc)
#pragma unroll
    for (int rr = 0; rr < 4; ++rr) av[oc][rr] = bv[oc * 16 + g * 4 + rr];
#pragma unroll
  for (int oc = 0; oc < 8; ++oc) {
#pragma unroll
    for (int cc = 0; cc < 8; ++cc) {
      bf16x8 a = ld_frag_g(wvb + (oc * 16 + r) * 256 + cc * 32 + g * 8);
      av[oc] = MFMA16(a, bx[cc], av[oc]);
    }
  }
#pragma unroll
  for (int oc = 0; oc < 8; ++oc) {
#pragma unroll
    for (int rr = 0; rr < 4; ++rr) {
      int o = oc * 16 + g * 4 + rr;
      Vm[((size_t)(b * 128 + o) << 12) + nl] = (__bf16)av[oc][rr];
    }
  }
}

// ---------------- K3: flash attention -> Ot [B][N][128] bf16 ---------------
__global__ __launch_bounds__(256) void k_flash(const __bf16* __restrict__ Qt,
                                               const __bf16* __restrict__ Kt,
                                               const __bf16* __restrict__ Vm,
                                               __bf16* __restrict__ Ot) {
  const int b = blockIdx.x >> 6;
  const int q0 = (blockIdx.x & 63) << 6;
  const int t = threadIdx.x, w = t >> 6, l = t & 63, r = l & 15, g = l >> 4;
  __shared__ __align__(16) char lds[23552];
  char* ktl = lds;                        // [32 m][128 c] bf16, XOR swizzled, 8192 B
  char* vtl = lds + 8192;                 // [128 c][40] bf16 (32 used), 10240 B
  char* ptl = lds + 18432 + w * 1280;     // per-wave [16][40] bf16

  bf16x8 aq[4];
  const __bf16* qrow = Qt + ((size_t)(b * NSP + q0 + w * 16 + r)) * 128;
#pragma unroll
  for (int cc = 0; cc < 4; ++cc) aq[cc] = ld_frag_g(qrow + cc * 32 + g * 8);

  f32x4 acc[8];
#pragma unroll
  for (int oc = 0; oc < 8; ++oc) acc[oc] = (f32x4){0.f, 0.f, 0.f, 0.f};
  float m_run[4] = {-1e30f, -1e30f, -1e30f, -1e30f};
  float l_run[4] = {0.f, 0.f, 0.f, 0.f};

  const __bf16* ktb = Kt + ((size_t)b << 19);
  const __bf16* vb = Vm + ((size_t)b << 19);

  for (int m0 = 0; m0 < NSP; m0 += 32) {
    __syncthreads();
    // stage K tile: 32 rows x 256 B, swizzled
#pragma unroll
    for (int p = 0; p < 2; ++p) {
      int u = p * 256 + t, row = u >> 4, seg = u & 15;
      int4 d = *(const int4*)(ktb + ((size_t)(m0 + row) << 7) + seg * 8);
      int byte = (row << 8) + (seg << 4);
      byte ^= (row & 7) << 4;
      *(int4*)(ktl + byte) = d;
    }
    // stage V tile: 128 rows x 64 B (pad stride 80 B)
#pragma unroll
    for (int p = 0; p < 2; ++p) {
      int u = p * 256 + t, c = u >> 2, mo = u & 3;
      int4 d = *(const int4*)(vb + ((size_t)c << 12) + m0 + mo * 8);
      *(int4*)(vtl + c * 80 + mo * 16) = d;
    }
    __syncthreads();

    f32x4 s0 = (f32x4){0.f, 0.f, 0.f, 0.f};
    f32x4 s1 = (f32x4){0.f, 0.f, 0.f, 0.f};
#pragma unroll
    for (int cc = 0; cc < 4; ++cc) {
      int byte0 = (r << 8) + cc * 64 + (g << 4);
      byte0 ^= (r & 7) << 4;
      bf16x8 bk0 = __builtin_bit_cast(bf16x8, *(int4*)(ktl + byte0));
      s0 = MFMA16(aq[cc], bk0, s0);
      int byte1 = ((16 + r) << 8) + cc * 64 + (g << 4);
      byte1 ^= (r & 7) << 4;
      bf16x8 bk1 = __builtin_bit_cast(bf16x8, *(int4*)(ktl + byte1));
      s1 = MFMA16(aq[cc], bk1, s1);
    }
    // online softmax; lane holds rows 4g+rr, cols r (s0) / 16+r (s1)
    float mx[4], alpha[4], rs[4];
#pragma unroll
    for (int rr = 0; rr < 4; ++rr) mx[rr] = fmaxf(s0[rr], s1[rr]);
#pragma unroll
    for (int msk = 1; msk <= 8; msk <<= 1)
#pragma unroll
      for (int rr = 0; rr < 4; ++rr) mx[rr] = fmaxf(mx[rr], __shfl_xor(mx[rr], msk));
#pragma unroll
    for (int rr = 0; rr < 4; ++rr) {
      float mn = fmaxf(m_run[rr], mx[rr]);
      alpha[rr] = exp2f((m_run[rr] - mn) * L2E);
      s0[rr] = exp2f((s0[rr] - mn) * L2E);
      s1[rr] = exp2f((s1[rr] - mn) * L2E);
      m_run[rr] = mn;
      rs[rr] = s0[rr] + s1[rr];
    }
#pragma unroll
    for (int msk = 1; msk <= 8; msk <<= 1)
#pragma unroll
      for (int rr = 0; rr < 4; ++rr) rs[rr] += __shfl_xor(rs[rr], msk);
#pragma unroll
    for (int rr = 0; rr < 4; ++rr) l_run[rr] = l_run[rr] * alpha[rr] + rs[rr];
#pragma unroll
    for (int oc = 0; oc < 8; ++oc)
#pragma unroll
      for (int rr = 0; rr < 4; ++rr) acc[oc][rr] *= alpha[rr];
    // transpose P via per-wave LDS (rows 4g+rr, 32 cols) -> A-fragment
#pragma unroll
    for (int rr = 0; rr < 4; ++rr) {
      *(__bf16*)(ptl + (g * 4 + rr) * 80 + r * 2) = (__bf16)s0[rr];
      *(__bf16*)(ptl + (g * 4 + rr) * 80 + (16 + r) * 2) = (__bf16)s1[rr];
    }
    bf16x8 ap = __builtin_bit_cast(bf16x8, *(int4*)(ptl + r * 80 + g * 16));
#pragma unroll
    for (int oc = 0; oc < 8; ++oc) {
      bf16x8 bv8 = __builtin_bit_cast(bf16x8, *(int4*)(vtl + (oc * 16 + r) * 80 + g * 16));
      acc[oc] = MFMA16(ap, bv8, acc[oc]);
    }
  }
  __syncthreads();
  float inv[4];
#pragma unroll
  for (int rr = 0; rr < 4; ++rr) inv[rr] = 1.0f / l_run[rr];
#pragma unroll
  for (int oc = 0; oc < 8; ++oc)
#pragma unroll
    for (int rr = 0; rr < 4; ++rr) acc[oc][rr] *= inv[rr];
  // reuse LDS: per-wave [16 n][128 c] transpose, coalesced store.
  // NOTE: flash D rows are q-rows (4g+rr), cols are channels (oc*16+r) -> this is
  // already [n][c]; store_tile_T's write indexing maps (row=r? no): write manually.
  char* otile = lds + (w << 12);
#pragma unroll
  for (int oc = 0; oc < 8; ++oc) {
#pragma unroll
    for (int rr = 0; rr < 4; ++rr) {
      int row = g * 4 + rr, col = oc * 16 + r;
      int byte = (row << 8) + (col << 1);
      byte ^= (row & 7) << 4;
      *(__bf16*)(otile + byte) = (__bf16)acc[oc][rr];
    }
  }
#pragma unroll
  for (int p = 0; p < 4; ++p) {
    int u = p * 64 + l, row = u >> 4, seg = u & 15;
    int byte = (row << 8) + (seg << 4);
    byte ^= (row & 7) << 4;
    int4 v = *(int4*)(otile + byte);
    *(int4*)(Ot + ((size_t)(b * NSP + q0 + w * 16 + row)) * 128 + seg * 8) = v;
  }
}

// ---------------- K4: out projection + residual -> d_out fp32 --------------
__global__ __launch_bounds__(256) void k_oproj(const __bf16* __restrict__ Ot,
                                               const __bf16* __restrict__ wob,
                                               const float* __restrict__ bo,
                                               const float* __restrict__ xq,
                                               float* __restrict__ out) {
  const int b = blockIdx.x >> 6;
  const int n0 = (blockIdx.x & 63) << 6;
  const int t = threadIdx.x, w = t >> 6, l = t & 63, r = l & 15, g = l >> 4;
  const int nl = n0 + (w << 4) + r;

  bf16x8 bfr[4];
  const __bf16* orow = Ot + ((size_t)(b * NSP + nl)) * 128;
#pragma unroll
  for (int cc = 0; cc < 4; ++cc) bfr[cc] = ld_frag_g(orow + cc * 32 + g * 8);
  f32x4 acc[8];
#pragma unroll
  for (int oc = 0; oc < 8; ++oc)
#pragma unroll
    for (int rr = 0; rr < 4; ++rr) acc[oc][rr] = bo[oc * 16 + g * 4 + rr];
#pragma unroll
  for (int oc = 0; oc < 8; ++oc) {
#pragma unroll
    for (int cc = 0; cc < 4; ++cc) {
      bf16x8 a = ld_frag_g(wob + (oc * 16 + r) * 128 + cc * 32 + g * 8);
      acc[oc] = MFMA16(a, bfr[cc], acc[oc]);
    }
  }
#pragma unroll
  for (int oc = 0; oc < 8; ++oc) {
#pragma unroll
    for (int rr = 0; rr < 4; ++rr) {
      int o = oc * 16 + g * 4 + rr;
      size_t idx = ((size_t)(b * 128 + o) << 12) + nl;
      out[idx] = acc[oc][rr] + xq[idx];
    }
  }
}

extern "C" void kernel_launch(void* const* d_in, const int* in_sizes, int n_in,
                              void* d_out, int out_size, void* d_ws, size_t ws_size,
                              hipStream_t stream) {
  const float* xq = (const float*)d_in[0];
  const float* xkv = (const float*)d_in[1];
  const float* Wq = (const float*)d_in[2];
  const float* bq = (const float*)d_in[3];
  const float* Wk = (const float*)d_in[4];
  const float* bk = (const float*)d_in[5];
  const float* Wv = (const float*)d_in[6];
  const float* bv = (const float*)d_in[7];
  const float* Wo = (const float*)d_in[8];
  const float* bo = (const float*)d_in[9];
  float* out = (float*)d_out;

  char* ws = (char*)d_ws;
  __bf16* wqb = (__bf16*)(ws);
  __bf16* wkb = (__bf16*)(ws + 32768);
  __bf16* wvb = (__bf16*)(ws + 98304);
  __bf16* wob = (__bf16*)(ws + 163840);
  float* bqs = (float*)(ws + 196608);
  __bf16* Qt = (__bf16*)(ws + 197120);
  __bf16* Kt = (__bf16*)(ws + 197120 + 4194304);
  __bf16* Vm = (__bf16*)(ws + 197120 + 2 * 4194304);
  __bf16* Ot = (__bf16*)(ws + 197120 + 3 * 4194304);

  k_prep<<<dim3(384), dim3(256), 0, stream>>>(Wq, bq, Wk, Wv, Wo, wqb, wkb, wvb, wob, bqs);
  k_qproj<<<dim3(256), dim3(256), 0, stream>>>(xq, wqb, bqs, Qt);
  k_kvproj<<<dim3(256), dim3(256), 0, stream>>>(xkv, wkb, wvb, bk, bv, Kt, Vm);
  k_flash<<<dim3(256), dim3(256), 0, stream>>>(Qt, Kt, Vm, Ot);
  k_oproj<<<dim3(256), dim3(256), 0, stream>>>(Ot, wob, bo, xq, out);
}

// Round 2
// 130.950 us; speedup vs baseline: 1.8093x; 1.8093x over previous
//
#include <hip/hip_runtime.h>
#include <hip/hip_bf16.h>

typedef __bf16 bf16x8 __attribute__((ext_vector_type(8)));
typedef float f32x4 __attribute__((ext_vector_type(4)));

#define MFMA16(a, b, c) __builtin_amdgcn_mfma_f32_16x16x32_bf16(a, b, c, 0, 0, 0)

static constexpr int NSP = 4096;   // H*W
static constexpr float SCALE_L2E = 0.25f * 1.4426950408889634f;  // SCALE * log2(e)

__device__ __forceinline__ bf16x8 ld_frag(const void* p) {
  int4 v = *(const int4*)p;
  return __builtin_bit_cast(bf16x8, v);
}

__device__ __forceinline__ void load_lds16(const void* g, void* l) {
  __builtin_amdgcn_global_load_lds(
      (const __attribute__((address_space(1))) unsigned*)g,
      (__attribute__((address_space(3))) unsigned*)l, 16, 0, 0);
}

// ---------------- K0: weight prep (fp32 -> bf16, fold SCALE*log2e into Wq/bq)
__global__ void k_prep(const float* __restrict__ Wq, const float* __restrict__ bq,
                       const float* __restrict__ Wk, const float* __restrict__ Wv,
                       const float* __restrict__ Wo,
                       __bf16* __restrict__ wqb, __bf16* __restrict__ wkb,
                       __bf16* __restrict__ wvb, __bf16* __restrict__ wob,
                       float* __restrict__ bqs) {
  int i = blockIdx.x * 256 + threadIdx.x;
  if (i < 16384)      wqb[i]          = (__bf16)(Wq[i] * SCALE_L2E);
  else if (i < 49152) wkb[i - 16384]  = (__bf16)Wk[i - 16384];
  else if (i < 81920) wvb[i - 49152]  = (__bf16)Wv[i - 49152];
  else if (i < 98304) wob[i - 81920]  = (__bf16)Wo[i - 81920];
  if (i < 128) bqs[i] = bq[i] * SCALE_L2E;
}

// Per-wave: write D[o][n] fragments transposed into a [16 n][128 o] bf16 LDS
// tile (XOR swizzled), then copy rows coalesced to dst.
// SWZ=false: undo the swizzle (global image linear).
// SWZ=true:  keep the swizzle (global image = swizzled, for flash's
//            global_load_lds + swizzled ds_read pair).
template <bool SWZ>
__device__ __forceinline__ void store_tile_T(char* myt, const f32x4* acc, int g, int r,
                                             __bf16* dst_base) {
#pragma unroll
  for (int oc = 0; oc < 8; ++oc) {
#pragma unroll
    for (int rr = 0; rr < 4; ++rr) {
      int o = oc * 16 + g * 4 + rr;
      int byte = (r << 8) + (o << 1);
      byte ^= (r & 7) << 4;
      *(__bf16*)(myt + byte) = (__bf16)acc[oc][rr];
    }
  }
  int l = g * 16 + r;
#pragma unroll
  for (int p = 0; p < 4; ++p) {
    int u = p * 64 + l, row = u >> 4, seg = u & 15;
    int byte = (row << 8) + (seg << 4);
    if (!SWZ) byte ^= (row & 7) << 4;
    int4 v = *(int4*)(myt + byte);
    *(int4*)(dst_base + row * 128 + seg * 8) = v;
  }
}

// ---------------- K1: Q projection -> Qt [B][N][128] bf16 (pre-scaled) -----
__global__ __launch_bounds__(256) void k_qproj(const float* __restrict__ xq,
                                               const __bf16* __restrict__ wqb,
                                               const float* __restrict__ bqs,
                                               __bf16* __restrict__ Qt) {
  const int b = blockIdx.x >> 6;
  const int n0 = (blockIdx.x & 63) << 6;
  const int t = threadIdx.x, w = t >> 6, l = t & 63, r = l & 15, g = l >> 4;
  const int nl = n0 + (w << 4) + r;
  __shared__ __align__(16) char lds[16384];
  char* myt = lds + (w << 12);

  const float* xb = xq + ((size_t)b << 19);
  bf16x8 bx[4];
#pragma unroll
  for (int cc = 0; cc < 4; ++cc) {
#pragma unroll
    for (int i = 0; i < 8; ++i) {
      int c = cc * 32 + g * 8 + i;
      bx[cc][i] = (__bf16)xb[c * 4096 + nl];
    }
  }
  f32x4 acc[8];
#pragma unroll
  for (int oc = 0; oc < 8; ++oc)
#pragma unroll
    for (int rr = 0; rr < 4; ++rr) acc[oc][rr] = bqs[oc * 16 + g * 4 + rr];
#pragma unroll
  for (int oc = 0; oc < 8; ++oc) {
#pragma unroll
    for (int cc = 0; cc < 4; ++cc) {
      bf16x8 a = ld_frag(wqb + (oc * 16 + r) * 128 + cc * 32 + g * 8);
      acc[oc] = MFMA16(a, bx[cc], acc[oc]);
    }
  }
  store_tile_T<false>(myt, acc, g, r, Qt + ((size_t)(b * NSP + n0 + w * 16)) * 128);
}

// ---------------- K2: K,V projection -> Kt (pre-swizzled), Vm (pre-swizzled)
__global__ __launch_bounds__(256) void k_kvproj(const float* __restrict__ xkv,
                                                const __bf16* __restrict__ wkb,
                                                const __bf16* __restrict__ wvb,
                                                const float* __restrict__ bk,
                                                const float* __restrict__ bv,
                                                __bf16* __restrict__ Kt,
                                                __bf16* __restrict__ Vm) {
  const int b = blockIdx.x >> 6;
  const int n0 = (blockIdx.x & 63) << 6;
  const int t = threadIdx.x, w = t >> 6, l = t & 63, r = l & 15, g = l >> 4;
  const int nl = n0 + (w << 4) + r;
  __shared__ __align__(16) char lds[16384];
  char* myt = lds + (w << 12);

  const float* xb = xkv + ((size_t)b << 20);
  bf16x8 bx[8];
#pragma unroll
  for (int cc = 0; cc < 8; ++cc) {
#pragma unroll
    for (int i = 0; i < 8; ++i) {
      int c = cc * 32 + g * 8 + i;
      bx[cc][i] = (__bf16)xb[(size_t)c * 4096 + nl];
    }
  }
  f32x4 acc[8];
#pragma unroll
  for (int oc = 0; oc < 8; ++oc)
#pragma unroll
    for (int rr = 0; rr < 4; ++rr) acc[oc][rr] = bk[oc * 16 + g * 4 + rr];
#pragma unroll
  for (int oc = 0; oc < 8; ++oc) {
#pragma unroll
    for (int cc = 0; cc < 8; ++cc) {
      bf16x8 a = ld_frag(wkb + (oc * 16 + r) * 256 + cc * 32 + g * 8);
      acc[oc] = MFMA16(a, bx[cc], acc[oc]);
    }
  }
  store_tile_T<true>(myt, acc, g, r, Kt + ((size_t)(b * NSP + n0 + w * 16)) * 128);

  f32x4 av[8];
#pragma unroll
  for (int oc = 0; oc < 8; ++oc)
#pragma unroll
    for (int rr = 0; rr < 4; ++rr) av[oc][rr] = bv[oc * 16 + g * 4 + rr];
#pragma unroll
  for (int oc = 0; oc < 8; ++oc) {
#pragma unroll
    for (int cc = 0; cc < 8; ++cc) {
      bf16x8 a = ld_frag(wvb + (oc * 16 + r) * 256 + cc * 32 + g * 8);
      av[oc] = MFMA16(a, bx[cc], av[oc]);
    }
  }
  // V stored [B][128][N], pre-swizzled within each 64-key block:
  // element for key n goes to n ^ ((ch&7)<<3)  (bits 3..5 only)
#pragma unroll
  for (int oc = 0; oc < 8; ++oc) {
#pragma unroll
    for (int rr = 0; rr < 4; ++rr) {
      int o = oc * 16 + g * 4 + rr;
      Vm[((size_t)(b * 128 + o) << 12) + (nl ^ ((o & 7) << 3))] = (__bf16)av[oc][rr];
    }
  }
}

// ---------------- K3: flash attention (split-K 2-way) ----------------------
// grid 256: bid&7 -> (batch, ksplit) combo (XCD-pinned), bid>>3 -> q-tile of 128
// 8 waves x 16 q-rows, KVBLK=64, double-buffered global_load_lds staging.
__global__ __launch_bounds__(512, 2) void k_flash(const __bf16* __restrict__ Qt,
                                                  const __bf16* __restrict__ Kt,
                                                  const __bf16* __restrict__ Vm,
                                                  __bf16* __restrict__ Op,
                                                  float2* __restrict__ Ml) {
  const int bid = blockIdx.x;
  const int combo = bid & 7, qtile = bid >> 3;
  const int b = combo >> 1, ks = combo & 1;
  const int q0 = qtile << 7;
  const int t = threadIdx.x, w = t >> 6, l = t & 63, r = l & 15, g = l >> 4;

  __shared__ __align__(16) char kl[2][16384];
  __shared__ __align__(16) char vl[2][16384];
  __shared__ __align__(16) char pl[8][2048];

  const int qrow = q0 + w * 16 + r;
  const __bf16* qp = Qt + ((size_t)(b * NSP + qrow)) * 128;
  bf16x8 aq[4];
#pragma unroll
  for (int cc = 0; cc < 4; ++cc) aq[cc] = ld_frag(qp + cc * 32 + g * 8);

  f32x4 acc[8];
#pragma unroll
  for (int oc = 0; oc < 8; ++oc) acc[oc] = (f32x4){0.f, 0.f, 0.f, 0.f};
  float m_run[4] = {-1e30f, -1e30f, -1e30f, -1e30f};
  float l_run[4] = {0.f, 0.f, 0.f, 0.f};

  const char* kbase = (const char*)(Kt + ((size_t)(b * NSP) + ks * 2048) * 128);
  const char* vbase = (const char*)(Vm + (size_t)b * 128 * NSP + ks * 2048);

  auto STAGE = [&](int bi, int tt) {
#pragma unroll
    for (int i = 0; i < 2; ++i) {  // K: 16 KB contiguous (pre-swizzled rows)
      int c = i * 8 + w;
      load_lds16(kbase + tt * 16384 + c * 1024 + l * 16, &kl[bi][c * 1024]);
    }
#pragma unroll
    for (int i = 0; i < 2; ++i) {  // V: 128 ch rows x 128 B
      int c0 = (i * 8 + w) * 8;
      int ch = c0 + (l >> 3);
      load_lds16(vbase + (size_t)ch * 8192 + tt * 128 + (l & 7) * 16,
                 &vl[bi][c0 * 128]);
    }
  };

  STAGE(0, 0);
  __syncthreads();

  const int nit = 32;
  for (int it = 0; it < nit; ++it) {
    const int cur = it & 1;
    if (it + 1 < nit) STAGE(cur ^ 1, it + 1);

    // ---- QK^T ----
    const char* kt = kl[cur];
    f32x4 s[4];
#pragma unroll
    for (int sg = 0; sg < 4; ++sg) s[sg] = (f32x4){0.f, 0.f, 0.f, 0.f};
    __builtin_amdgcn_s_setprio(1);
#pragma unroll
    for (int cc = 0; cc < 4; ++cc) {
#pragma unroll
      for (int sg = 0; sg < 4; ++sg) {
        int addr = ((sg * 16 + r) << 8) + ((cc * 64 + (g << 4)) ^ ((r & 7) << 4));
        s[sg] = MFMA16(aq[cc], ld_frag(kt + addr), s[sg]);
      }
    }
    __builtin_amdgcn_s_setprio(0);

    // ---- online softmax (exp2 domain; S already scaled by SCALE*log2e) ----
    float mx[4], mn[4], al[4], rs[4];
#pragma unroll
    for (int rr = 0; rr < 4; ++rr)
      mx[rr] = fmaxf(fmaxf(s[0][rr], s[1][rr]), fmaxf(s[2][rr], s[3][rr]));
#pragma unroll
    for (int msk = 1; msk <= 8; msk <<= 1)
#pragma unroll
      for (int rr = 0; rr < 4; ++rr) mx[rr] = fmaxf(mx[rr], __shfl_xor(mx[rr], msk));
#pragma unroll
    for (int rr = 0; rr < 4; ++rr) {
      mn[rr] = fmaxf(m_run[rr], mx[rr]);
      al[rr] = exp2f(m_run[rr] - mn[rr]);
      m_run[rr] = mn[rr];
    }
#pragma unroll
    for (int sg = 0; sg < 4; ++sg)
#pragma unroll
      for (int rr = 0; rr < 4; ++rr) s[sg][rr] = exp2f(s[sg][rr] - mn[rr]);
#pragma unroll
    for (int rr = 0; rr < 4; ++rr)
      rs[rr] = (s[0][rr] + s[1][rr]) + (s[2][rr] + s[3][rr]);
#pragma unroll
    for (int msk = 1; msk <= 8; msk <<= 1)
#pragma unroll
      for (int rr = 0; rr < 4; ++rr) rs[rr] += __shfl_xor(rs[rr], msk);
#pragma unroll
    for (int rr = 0; rr < 4; ++rr) l_run[rr] = l_run[rr] * al[rr] + rs[rr];
#pragma unroll
    for (int oc = 0; oc < 8; ++oc)
#pragma unroll
      for (int rr = 0; rr < 4; ++rr) acc[oc][rr] *= al[rr];

    // ---- P transpose via per-wave LDS (swizzled [16][128B]) ----
    char* ptl = pl[w];
#pragma unroll
    for (int sg = 0; sg < 4; ++sg)
#pragma unroll
      for (int rr = 0; rr < 4; ++rr) {
        int row = g * 4 + rr;
        int byte = (row << 7) + (((sg * 16 + r) << 1) ^ ((row & 7) << 4));
        *(__bf16*)(ptl + byte) = (__bf16)s[sg][rr];
      }
    bf16x8 pa[2];
#pragma unroll
    for (int kk = 0; kk < 2; ++kk)
      pa[kk] = ld_frag(ptl + (r << 7) + ((kk * 64 + (g << 4)) ^ ((r & 7) << 4)));

    // ---- PV ----
    const char* vt = vl[cur];
    __builtin_amdgcn_s_setprio(1);
#pragma unroll
    for (int kk = 0; kk < 2; ++kk)
#pragma unroll
      for (int oc = 0; oc < 8; ++oc) {
        int addr = ((oc * 16 + r) << 7) + ((kk * 64 + (g << 4)) ^ ((r & 7) << 4));
        acc[oc] = MFMA16(pa[kk], ld_frag(vt + addr), acc[oc]);
      }
    __builtin_amdgcn_s_setprio(0);
    __syncthreads();
  }

  // ---- partial store (unnormalized O, plus m/l) ----
  __bf16* opb = Op + ((size_t)(ks * 4 + b) * NSP + q0 + w * 16 + g * 4) * 128;
#pragma unroll
  for (int rr = 0; rr < 4; ++rr)
#pragma unroll
    for (int oc = 0; oc < 8; ++oc)
      opb[rr * 128 + oc * 16 + r] = (__bf16)acc[oc][rr];
  if (r == 0) {
#pragma unroll
    for (int rr = 0; rr < 4; ++rr)
      Ml[(size_t)(ks * 4 + b) * NSP + q0 + w * 16 + g * 4 + rr] =
          make_float2(m_run[rr], l_run[rr]);
  }
}

// ---------------- K4: combine splits + out projection + residual -----------
__global__ __launch_bounds__(256) void k_oproj(const __bf16* __restrict__ Op,
                                               const float2* __restrict__ Ml,
                                               const __bf16* __restrict__ wob,
                                               const float* __restrict__ bo,
                                               const float* __restrict__ xq,
                                               float* __restrict__ out) {
  const int b = blockIdx.x >> 6;
  const int n0 = (blockIdx.x & 63) << 6;
  const int t = threadIdx.x, w = t >> 6, l = t & 63, r = l & 15, g = l >> 4;
  const int nl = n0 + (w << 4) + r;

  const __bf16* o0 = Op + ((size_t)b * NSP + nl) * 128;
  const __bf16* o1 = Op + ((size_t)(4 + b) * NSP + nl) * 128;
  float2 e0 = Ml[(size_t)b * NSP + nl];
  float2 e1 = Ml[(size_t)(4 + b) * NSP + nl];
  float M = fmaxf(e0.x, e1.x);
  float w0 = exp2f(e0.x - M), w1 = exp2f(e1.x - M);
  float inv = 1.f / (e0.y * w0 + e1.y * w1);
  w0 *= inv;
  w1 *= inv;

  bf16x8 bfr[4];
#pragma unroll
  for (int cc = 0; cc < 4; ++cc) {
    bf16x8 a0 = ld_frag(o0 + cc * 32 + g * 8);
    bf16x8 a1 = ld_frag(o1 + cc * 32 + g * 8);
#pragma unroll
    for (int j = 0; j < 8; ++j)
      bfr[cc][j] = (__bf16)((float)a0[j] * w0 + (float)a1[j] * w1);
  }

  f32x4 acc[8];
#pragma unroll
  for (int oc = 0; oc < 8; ++oc)
#pragma unroll
    for (int rr = 0; rr < 4; ++rr) acc[oc][rr] = bo[oc * 16 + g * 4 + rr];
#pragma unroll
  for (int oc = 0; oc < 8; ++oc) {
#pragma unroll
    for (int cc = 0; cc < 4; ++cc) {
      bf16x8 a = ld_frag(wob + (oc * 16 + r) * 128 + cc * 32 + g * 8);
      acc[oc] = MFMA16(a, bfr[cc], acc[oc]);
    }
  }
#pragma unroll
  for (int oc = 0; oc < 8; ++oc) {
#pragma unroll
    for (int rr = 0; rr < 4; ++rr) {
      int o = oc * 16 + g * 4 + rr;
      size_t idx = ((size_t)(b * 128 + o) << 12) + nl;
      out[idx] = acc[oc][rr] + xq[idx];
    }
  }
}

extern "C" void kernel_launch(void* const* d_in, const int* in_sizes, int n_in,
                              void* d_out, int out_size, void* d_ws, size_t ws_size,
                              hipStream_t stream) {
  const float* xq = (const float*)d_in[0];
  const float* xkv = (const float*)d_in[1];
  const float* Wq = (const float*)d_in[2];
  const float* bq = (const float*)d_in[3];
  const float* Wk = (const float*)d_in[4];
  const float* bk = (const float*)d_in[5];
  const float* Wv = (const float*)d_in[6];
  const float* bv = (const float*)d_in[7];
  const float* Wo = (const float*)d_in[8];
  const float* bo = (const float*)d_in[9];
  float* out = (float*)d_out;

  char* ws = (char*)d_ws;
  __bf16* wqb = (__bf16*)(ws);
  __bf16* wkb = (__bf16*)(ws + 32768);
  __bf16* wvb = (__bf16*)(ws + 98304);
  __bf16* wob = (__bf16*)(ws + 163840);
  float* bqs = (float*)(ws + 196608);
  __bf16* Qt = (__bf16*)(ws + 197120);
  __bf16* Kt = (__bf16*)(ws + 197120 + 4194304);
  __bf16* Vm = (__bf16*)(ws + 197120 + 2 * 4194304);
  __bf16* Op = (__bf16*)(ws + 197120 + 3 * 4194304);
  float2* Ml = (float2*)(ws + 197120 + 3 * 4194304 + 8388608);

  k_prep<<<dim3(384), dim3(256), 0, stream>>>(Wq, bq, Wk, Wv, Wo, wqb, wkb, wvb, wob, bqs);
  k_qproj<<<dim3(256), dim3(256), 0, stream>>>(xq, wqb, bqs, Qt);
  k_kvproj<<<dim3(256), dim3(256), 0, stream>>>(xkv, wkb, wvb, bk, bv, Kt, Vm);
  k_flash<<<dim3(256), dim3(512), 0, stream>>>(Qt, Kt, Vm, Op, Ml);
  k_oproj<<<dim3(256), dim3(256), 0, stream>>>(Op, Ml, wob, bo, xq, out);
}

// Round 3
// 99.989 us; speedup vs baseline: 2.3696x; 1.3097x over previous
//
#include <hip/hip_runtime.h>
#include <hip/hip_bf16.h>

typedef __bf16 bf16x8 __attribute__((ext_vector_type(8)));
typedef float f32x4 __attribute__((ext_vector_type(4)));

#define MFMA16(a, b, c) __builtin_amdgcn_mfma_f32_16x16x32_bf16(a, b, c, 0, 0, 0)

static constexpr int NSP = 4096;   // H*W
static constexpr float SCALE_L2E = 0.25f * 1.4426950408889634f;  // SCALE * log2(e)

__device__ __forceinline__ bf16x8 ld_frag(const void* p) {
  int4 v = *(const int4*)p;
  return __builtin_bit_cast(bf16x8, v);
}

__device__ __forceinline__ unsigned pk2(float a, float b) {
  unsigned short x = __builtin_bit_cast(unsigned short, (__bf16)a);
  unsigned short y = __builtin_bit_cast(unsigned short, (__bf16)b);
  return (unsigned)x | ((unsigned)y << 16);
}

__device__ __forceinline__ void load_lds16(const void* g, void* l) {
  __builtin_amdgcn_global_load_lds(
      (const __attribute__((address_space(1))) unsigned*)g,
      (__attribute__((address_space(3))) unsigned*)l, 16, 0, 0);
}

// ---------------- K0: weight prep (fp32 -> bf16, fold SCALE*log2e into Wq/bq)
__global__ void k_prep(const float* __restrict__ Wq, const float* __restrict__ bq,
                       const float* __restrict__ Wk, const float* __restrict__ Wv,
                       const float* __restrict__ Wo,
                       __bf16* __restrict__ wqb, __bf16* __restrict__ wkb,
                       __bf16* __restrict__ wvb, __bf16* __restrict__ wob,
                       float* __restrict__ bqs) {
  int i = blockIdx.x * 256 + threadIdx.x;
  if (i < 16384)      wqb[i]          = (__bf16)(Wq[i] * SCALE_L2E);
  else if (i < 49152) wkb[i - 16384]  = (__bf16)Wk[i - 16384];
  else if (i < 81920) wvb[i - 49152]  = (__bf16)Wv[i - 49152];
  else if (i < 98304) wob[i - 81920]  = (__bf16)Wo[i - 81920];
  if (i < 128) bqs[i] = bq[i] * SCALE_L2E;
}

// Per-wave: write D[o][n] fragments transposed into a [16 n][128 o] bf16 LDS
// tile (XOR swizzled), then copy rows coalesced to dst.
template <bool SWZ>
__device__ __forceinline__ void store_tile_T(char* myt, const f32x4* acc, int g, int r,
                                             __bf16* dst_base) {
#pragma unroll
  for (int oc = 0; oc < 8; ++oc) {
#pragma unroll
    for (int rr = 0; rr < 4; ++rr) {
      int o = oc * 16 + g * 4 + rr;
      int byte = (r << 8) + (o << 1);
      byte ^= (r & 7) << 4;
      *(__bf16*)(myt + byte) = (__bf16)acc[oc][rr];
    }
  }
  int l = g * 16 + r;
#pragma unroll
  for (int p = 0; p < 4; ++p) {
    int u = p * 64 + l, row = u >> 4, seg = u & 15;
    int byte = (row << 8) + (seg << 4);
    if (!SWZ) byte ^= (row & 7) << 4;
    int4 v = *(int4*)(myt + byte);
    *(int4*)(dst_base + row * 128 + seg * 8) = v;
  }
}

// ---------------- K1: Q projection -> Qt [B][N][128] bf16 (pre-scaled) -----
__global__ __launch_bounds__(256) void k_qproj(const float* __restrict__ xq,
                                               const __bf16* __restrict__ wqb,
                                               const float* __restrict__ bqs,
                                               __bf16* __restrict__ Qt) {
  const int b = blockIdx.x >> 6;
  const int n0 = (blockIdx.x & 63) << 6;
  const int t = threadIdx.x, w = t >> 6, l = t & 63, r = l & 15, g = l >> 4;
  const int nl = n0 + (w << 4) + r;
  __shared__ __align__(16) char lds[16384];
  char* myt = lds + (w << 12);

  const float* xb = xq + ((size_t)b << 19);
  bf16x8 bx[4];
#pragma unroll
  for (int cc = 0; cc < 4; ++cc) {
#pragma unroll
    for (int i = 0; i < 8; ++i) {
      int c = cc * 32 + g * 8 + i;
      bx[cc][i] = (__bf16)xb[c * 4096 + nl];
    }
  }
  f32x4 acc[8];
#pragma unroll
  for (int oc = 0; oc < 8; ++oc)
#pragma unroll
    for (int rr = 0; rr < 4; ++rr) acc[oc][rr] = bqs[oc * 16 + g * 4 + rr];
#pragma unroll
  for (int oc = 0; oc < 8; ++oc) {
#pragma unroll
    for (int cc = 0; cc < 4; ++cc) {
      bf16x8 a = ld_frag(wqb + (oc * 16 + r) * 128 + cc * 32 + g * 8);
      acc[oc] = MFMA16(a, bx[cc], acc[oc]);
    }
  }
  store_tile_T<false>(myt, acc, g, r, Qt + ((size_t)(b * NSP + n0 + w * 16)) * 128);
}

// ---------------- K2: K,V projection -> Kt (pre-swizzled), Vm (pre-swizzled)
__global__ __launch_bounds__(256) void k_kvproj(const float* __restrict__ xkv,
                                                const __bf16* __restrict__ wkb,
                                                const __bf16* __restrict__ wvb,
                                                const float* __restrict__ bk,
                                                const float* __restrict__ bv,
                                                __bf16* __restrict__ Kt,
                                                __bf16* __restrict__ Vm) {
  const int b = blockIdx.x >> 6;
  const int n0 = (blockIdx.x & 63) << 6;
  const int t = threadIdx.x, w = t >> 6, l = t & 63, r = l & 15, g = l >> 4;
  const int nl = n0 + (w << 4) + r;
  __shared__ __align__(16) char lds[16384];
  char* myt = lds + (w << 12);

  const float* xb = xkv + ((size_t)b << 20);
  bf16x8 bx[8];
#pragma unroll
  for (int cc = 0; cc < 8; ++cc) {
#pragma unroll
    for (int i = 0; i < 8; ++i) {
      int c = cc * 32 + g * 8 + i;
      bx[cc][i] = (__bf16)xb[(size_t)c * 4096 + nl];
    }
  }
  f32x4 acc[8];
#pragma unroll
  for (int oc = 0; oc < 8; ++oc)
#pragma unroll
    for (int rr = 0; rr < 4; ++rr) acc[oc][rr] = bk[oc * 16 + g * 4 + rr];
#pragma unroll
  for (int oc = 0; oc < 8; ++oc) {
#pragma unroll
    for (int cc = 0; cc < 8; ++cc) {
      bf16x8 a = ld_frag(wkb + (oc * 16 + r) * 256 + cc * 32 + g * 8);
      acc[oc] = MFMA16(a, bx[cc], acc[oc]);
    }
  }
  store_tile_T<true>(myt, acc, g, r, Kt + ((size_t)(b * NSP + n0 + w * 16)) * 128);

  f32x4 av[8];
#pragma unroll
  for (int oc = 0; oc < 8; ++oc)
#pragma unroll
    for (int rr = 0; rr < 4; ++rr) av[oc][rr] = bv[oc * 16 + g * 4 + rr];
#pragma unroll
  for (int oc = 0; oc < 8; ++oc) {
#pragma unroll
    for (int cc = 0; cc < 8; ++cc) {
      bf16x8 a = ld_frag(wvb + (oc * 16 + r) * 256 + cc * 32 + g * 8);
      av[oc] = MFMA16(a, bx[cc], av[oc]);
    }
  }
  // V stored [B][128][N], pre-swizzled: key n at n ^ ((ch&7)<<3)
#pragma unroll
  for (int oc = 0; oc < 8; ++oc) {
#pragma unroll
    for (int rr = 0; rr < 4; ++rr) {
      int o = oc * 16 + g * 4 + rr;
      Vm[((size_t)(b * 128 + o) << 12) + (nl ^ ((o & 7) << 3))] = (__bf16)av[oc][rr];
    }
  }
}

// ---------------- K3: flash attention (swapped operands, 32 q-rows/wave) ---
// grid = 4*SPLIT combos * 16 qtiles. 8 waves * 32 q-rows = 256 q-rows/block.
// Swapped QK^T: s = mfma(K,Q) -> lane holds S^T[keys][query=r]; softmax is
// per-lane + 2 shfl. PV: acc = mfma(V^T, P^T) -> O^T[ch][query].
template <int SPLIT>
__global__ __launch_bounds__(512, 2) void k_flash(const __bf16* __restrict__ Qt,
                                                  const __bf16* __restrict__ Kt,
                                                  const __bf16* __restrict__ Vm,
                                                  __bf16* __restrict__ Op,
                                                  float2* __restrict__ Ml) {
  const int bid = blockIdx.x;
  const int combo = bid & (4 * SPLIT - 1), qtile = bid / (4 * SPLIT);
  const int b = combo & 3, ks = combo >> 2;
  const int q0 = qtile << 8;
  const int NK = NSP / SPLIT;
  const int t = threadIdx.x, w = t >> 6, l = t & 63, r = l & 15, g = l >> 4;

  __shared__ __align__(16) char kl[2][16384];
  __shared__ __align__(16) char vl[2][16384];
  __shared__ __align__(16) char pl[8][4096];

  // Q fragments for two row-groups (queries q0+w*32+r and +16+r)
  bf16x8 aq0[4], aq1[4];
  {
    const __bf16* qp0 = Qt + ((size_t)(b * NSP + q0 + w * 32 + r)) * 128;
#pragma unroll
    for (int cc = 0; cc < 4; ++cc) {
      aq0[cc] = ld_frag(qp0 + cc * 32 + g * 8);
      aq1[cc] = ld_frag(qp0 + 16 * 128 + cc * 32 + g * 8);
    }
  }

  f32x4 acc0[8], acc1[8];
#pragma unroll
  for (int oc = 0; oc < 8; ++oc) {
    acc0[oc] = (f32x4){0.f, 0.f, 0.f, 0.f};
    acc1[oc] = (f32x4){0.f, 0.f, 0.f, 0.f};
  }
  float m0 = -1e30f, l0 = 0.f, m1 = -1e30f, l1 = 0.f;

  const char* kbase = (const char*)(Kt + ((size_t)(b * NSP) + ks * NK) * 128);
  const char* vbase = (const char*)(Vm + (size_t)b * 128 * NSP + ks * NK);

  auto STAGE = [&](int bi, int tt) {
#pragma unroll
    for (int i = 0; i < 2; ++i) {  // K: 16 KB (pre-swizzled rows)
      int c = i * 8 + w;
      load_lds16(kbase + tt * 16384 + c * 1024 + l * 16, &kl[bi][c * 1024]);
    }
#pragma unroll
    for (int i = 0; i < 2; ++i) {  // V: 128 ch rows x 128 B
      int c0 = (i * 8 + w) * 8;
      int ch = c0 + (l >> 3);
      load_lds16(vbase + (size_t)ch * 8192 + tt * 128 + (l & 7) * 16,
                 &vl[bi][c0 * 128]);
    }
  };

  STAGE(0, 0);
  __syncthreads();

  const int nit = NK / 64;
  for (int it = 0; it < nit; ++it) {
    const int cur = it & 1;
    if (it + 1 < nit) STAGE(cur ^ 1, it + 1);

    // ---- QK^T (swapped: A=K, B=Q). kf reused for both row-groups ----
    const char* kt = kl[cur];
    f32x4 s0[4], s1[4];
#pragma unroll
    for (int sg = 0; sg < 4; ++sg) {
      s0[sg] = (f32x4){0.f, 0.f, 0.f, 0.f};
      s1[sg] = (f32x4){0.f, 0.f, 0.f, 0.f};
    }
    __builtin_amdgcn_s_setprio(1);
#pragma unroll
    for (int cc = 0; cc < 4; ++cc) {
#pragma unroll
      for (int sg = 0; sg < 4; ++sg) {
        int addr = ((sg * 16 + r) << 8) + ((cc * 64 + (g << 4)) ^ ((r & 7) << 4));
        bf16x8 kf = ld_frag(kt + addr);
        s0[sg] = MFMA16(kf, aq0[cc], s0[sg]);
        s1[sg] = MFMA16(kf, aq1[cc], s1[sg]);
      }
    }
    __builtin_amdgcn_s_setprio(0);

    // ---- per-lane online softmax (lane = one query per set) ----
    float mx0 = s0[0][0], mx1 = s1[0][0];
#pragma unroll
    for (int sg = 0; sg < 4; ++sg)
#pragma unroll
      for (int rr = 0; rr < 4; ++rr) {
        mx0 = fmaxf(mx0, s0[sg][rr]);
        mx1 = fmaxf(mx1, s1[sg][rr]);
      }
    mx0 = fmaxf(mx0, __shfl_xor(mx0, 16));
    mx0 = fmaxf(mx0, __shfl_xor(mx0, 32));
    mx1 = fmaxf(mx1, __shfl_xor(mx1, 16));
    mx1 = fmaxf(mx1, __shfl_xor(mx1, 32));
    // defer-max: rescale only when a lane's max grew past threshold
    if (__any(fmaxf(mx0 - m0, mx1 - m1) > 8.f)) {
      float n0f = fmaxf(m0, mx0), n1f = fmaxf(m1, mx1);
      float a0 = exp2f(m0 - n0f), a1 = exp2f(m1 - n1f);
      m0 = n0f; m1 = n1f;
      l0 *= a0; l1 *= a1;
#pragma unroll
      for (int oc = 0; oc < 8; ++oc) {
#pragma unroll
        for (int rr = 0; rr < 4; ++rr) {
          acc0[oc][rr] *= a0;
          acc1[oc][rr] *= a1;
        }
      }
    }
    float rs0 = 0.f, rs1 = 0.f;
#pragma unroll
    for (int sg = 0; sg < 4; ++sg)
#pragma unroll
      for (int rr = 0; rr < 4; ++rr) {
        s0[sg][rr] = exp2f(s0[sg][rr] - m0);
        s1[sg][rr] = exp2f(s1[sg][rr] - m1);
        rs0 += s0[sg][rr];
        rs1 += s1[sg][rr];
      }
    rs0 += __shfl_xor(rs0, 16);
    rs0 += __shfl_xor(rs0, 32);
    rs1 += __shfl_xor(rs1, 16);
    rs1 += __shfl_xor(rs1, 32);
    l0 += rs0;
    l1 += rs1;

    // ---- P -> bf16, per-wave LDS transpose ([32 q][64 k], swizzled) ----
    char* ptl = pl[w];
#pragma unroll
    for (int sg = 0; sg < 4; ++sg) {
      uint2 v0, v1;
      v0.x = pk2(s0[sg][0], s0[sg][1]);
      v0.y = pk2(s0[sg][2], s0[sg][3]);
      v1.x = pk2(s1[sg][0], s1[sg][1]);
      v1.y = pk2(s1[sg][2], s1[sg][3]);
      int off = (sg * 32 + g * 8) ^ ((r & 7) << 4);
      *(uint2*)(ptl + (r << 7) + off) = v0;
      *(uint2*)(ptl + ((16 + r) << 7) + off) = v1;
    }
    bf16x8 pb0[2], pb1[2];
#pragma unroll
    for (int kk = 0; kk < 2; ++kk) {
      int off = (kk * 64 + (g << 4)) ^ ((r & 7) << 4);
      pb0[kk] = ld_frag(ptl + (r << 7) + off);
      pb1[kk] = ld_frag(ptl + ((16 + r) << 7) + off);
    }

    // ---- PV (swapped: A=V^T, B=P^T). vf reused for both row-groups ----
    const char* vt = vl[cur];
    __builtin_amdgcn_s_setprio(1);
#pragma unroll
    for (int kk = 0; kk < 2; ++kk) {
#pragma unroll
      for (int oc = 0; oc < 8; ++oc) {
        int addr = ((oc * 16 + r) << 7) + ((kk * 64 + (g << 4)) ^ ((r & 7) << 4));
        bf16x8 vf = ld_frag(vt + addr);
        acc0[oc] = MFMA16(vf, pb0[kk], acc0[oc]);
        acc1[oc] = MFMA16(vf, pb1[kk], acc1[oc]);
      }
    }
    __builtin_amdgcn_s_setprio(0);
    __syncthreads();
  }

  // ---- partial store: lane holds O^T[ch=oc*16+4g+rr][q] for q=r / 16+r ----
  const size_t prow = (size_t)((ks * 4 + b) * NSP + q0 + w * 32 + r) * 128;
  __bf16* op0 = Op + prow;
  __bf16* op1 = Op + prow + 16 * 128;
#pragma unroll
  for (int oc = 0; oc < 8; ++oc) {
    uint2 v0, v1;
    v0.x = pk2(acc0[oc][0], acc0[oc][1]);
    v0.y = pk2(acc0[oc][2], acc0[oc][3]);
    v1.x = pk2(acc1[oc][0], acc1[oc][1]);
    v1.y = pk2(acc1[oc][2], acc1[oc][3]);
    *(uint2*)(op0 + oc * 16 + 4 * g) = v0;
    *(uint2*)(op1 + oc * 16 + 4 * g) = v1;
  }
  if (g == 0) {
    size_t mlrow = (size_t)(ks * 4 + b) * NSP + q0 + w * 32 + r;
    Ml[mlrow] = make_float2(m0, l0);
    Ml[mlrow + 16] = make_float2(m1, l1);
  }
}

// ---------------- K4: combine splits + out projection + residual -----------
template <int SPLIT>
__global__ __launch_bounds__(256) void k_oproj(const __bf16* __restrict__ Op,
                                               const float2* __restrict__ Ml,
                                               const __bf16* __restrict__ wob,
                                               const float* __restrict__ bo,
                                               const float* __restrict__ xq,
                                               float* __restrict__ out) {
  const int b = blockIdx.x >> 6;
  const int n0 = (blockIdx.x & 63) << 6;
  const int t = threadIdx.x, w = t >> 6, l = t & 63, r = l & 15, g = l >> 4;
  const int nl = n0 + (w << 4) + r;

  float2 e[SPLIT];
  float M = -1e30f;
#pragma unroll
  for (int s = 0; s < SPLIT; ++s) {
    e[s] = Ml[(size_t)(s * 4 + b) * NSP + nl];
    M = fmaxf(M, e[s].x);
  }
  float wk[SPLIT], den = 0.f;
#pragma unroll
  for (int s = 0; s < SPLIT; ++s) {
    wk[s] = exp2f(e[s].x - M);
    den += e[s].y * wk[s];
  }
  float inv = 1.f / den;
#pragma unroll
  for (int s = 0; s < SPLIT; ++s) wk[s] *= inv;

  bf16x8 bfr[4];
#pragma unroll
  for (int cc = 0; cc < 4; ++cc) {
    float a8[8];
#pragma unroll
    for (int j = 0; j < 8; ++j) a8[j] = 0.f;
#pragma unroll
    for (int s = 0; s < SPLIT; ++s) {
      bf16x8 a = ld_frag(Op + ((size_t)(s * 4 + b) * NSP + nl) * 128 + cc * 32 + g * 8);
#pragma unroll
      for (int j = 0; j < 8; ++j) a8[j] += (float)a[j] * wk[s];
    }
#pragma unroll
    for (int j = 0; j < 8; ++j) bfr[cc][j] = (__bf16)a8[j];
  }

  f32x4 acc[8];
#pragma unroll
  for (int oc = 0; oc < 8; ++oc)
#pragma unroll
    for (int rr = 0; rr < 4; ++rr) acc[oc][rr] = bo[oc * 16 + g * 4 + rr];
#pragma unroll
  for (int oc = 0; oc < 8; ++oc) {
#pragma unroll
    for (int cc = 0; cc < 4; ++cc) {
      bf16x8 a = ld_frag(wob + (oc * 16 + r) * 128 + cc * 32 + g * 8);
      acc[oc] = MFMA16(a, bfr[cc], acc[oc]);
    }
  }
#pragma unroll
  for (int oc = 0; oc < 8; ++oc) {
#pragma unroll
    for (int rr = 0; rr < 4; ++rr) {
      int o = oc * 16 + g * 4 + rr;
      size_t idx = ((size_t)(b * 128 + o) << 12) + nl;
      out[idx] = acc[oc][rr] + xq[idx];
    }
  }
}

extern "C" void kernel_launch(void* const* d_in, const int* in_sizes, int n_in,
                              void* d_out, int out_size, void* d_ws, size_t ws_size,
                              hipStream_t stream) {
  const float* xq = (const float*)d_in[0];
  const float* xkv = (const float*)d_in[1];
  const float* Wq = (const float*)d_in[2];
  const float* bq = (const float*)d_in[3];
  const float* Wk = (const float*)d_in[4];
  const float* bk = (const float*)d_in[5];
  const float* Wv = (const float*)d_in[6];
  const float* bv = (const float*)d_in[7];
  const float* Wo = (const float*)d_in[8];
  const float* bo = (const float*)d_in[9];
  float* out = (float*)d_out;

  char* ws = (char*)d_ws;
  __bf16* wqb = (__bf16*)(ws);
  __bf16* wkb = (__bf16*)(ws + 32768);
  __bf16* wvb = (__bf16*)(ws + 98304);
  __bf16* wob = (__bf16*)(ws + 163840);
  float* bqs = (float*)(ws + 196608);
  __bf16* Qt = (__bf16*)(ws + 197120);
  __bf16* Kt = (__bf16*)(ws + 197120 + 4194304);
  __bf16* Vm = (__bf16*)(ws + 197120 + 2 * 4194304);
  __bf16* Op = (__bf16*)(ws + 197120 + 3 * 4194304);
  float2* Ml = (float2*)(ws + 197120 + 3 * 4194304 + 16777216);

  k_prep<<<dim3(384), dim3(256), 0, stream>>>(Wq, bq, Wk, Wv, Wo, wqb, wkb, wvb, wob, bqs);
  k_qproj<<<dim3(256), dim3(256), 0, stream>>>(xq, wqb, bqs, Qt);
  k_kvproj<<<dim3(256), dim3(256), 0, stream>>>(xkv, wkb, wvb, bk, bv, Kt, Vm);

  const size_t need4 = 197120ull + 3ull * 4194304 + 16777216 + 524288;
  if (ws_size >= need4) {
    k_flash<4><<<dim3(256), dim3(512), 0, stream>>>(Qt, Kt, Vm, Op, Ml);
    k_oproj<4><<<dim3(256), dim3(256), 0, stream>>>(Op, Ml, wob, bo, xq, out);
  } else {
    k_flash<2><<<dim3(128), dim3(512), 0, stream>>>(Qt, Kt, Vm, Op, Ml);
    k_oproj<2><<<dim3(256), dim3(256), 0, stream>>>(Op, Ml, wob, bo, xq, out);
  }
}

// Round 4
// 95.843 us; speedup vs baseline: 2.4721x; 1.0433x over previous
//
#include <hip/hip_runtime.h>
#include <hip/hip_bf16.h>

typedef __bf16 bf16x8 __attribute__((ext_vector_type(8)));
typedef float f32x4 __attribute__((ext_vector_type(4)));

#define MFMA16(a, b, c) __builtin_amdgcn_mfma_f32_16x16x32_bf16(a, b, c, 0, 0, 0)

static constexpr int NSP = 4096;   // H*W
static constexpr float SCALE_L2E = 0.25f * 1.4426950408889634f;  // SCALE * log2(e)

__device__ __forceinline__ bf16x8 ld_frag(const void* p) {
  int4 v = *(const int4*)p;
  return __builtin_bit_cast(bf16x8, v);
}

__device__ __forceinline__ unsigned pk2(float a, float b) {
  unsigned short x = __builtin_bit_cast(unsigned short, (__bf16)a);
  unsigned short y = __builtin_bit_cast(unsigned short, (__bf16)b);
  return (unsigned)x | ((unsigned)y << 16);
}

__device__ __forceinline__ void load_lds16(const void* g, void* l) {
  __builtin_amdgcn_global_load_lds(
      (const __attribute__((address_space(1))) unsigned*)g,
      (__attribute__((address_space(3))) unsigned*)l, 16, 0, 0);
}

// ---------------- K0: weight prep (fp32 -> bf16, fold SCALE*log2e into Wq/bq)
__global__ void k_prep(const float* __restrict__ Wq, const float* __restrict__ bq,
                       const float* __restrict__ Wk, const float* __restrict__ Wv,
                       const float* __restrict__ Wo,
                       __bf16* __restrict__ wqb, __bf16* __restrict__ wkb,
                       __bf16* __restrict__ wvb, __bf16* __restrict__ wob,
                       float* __restrict__ bqs) {
  int i = blockIdx.x * 256 + threadIdx.x;
  if (i < 16384)      wqb[i]          = (__bf16)(Wq[i] * SCALE_L2E);
  else if (i < 49152) wkb[i - 16384]  = (__bf16)Wk[i - 16384];
  else if (i < 81920) wvb[i - 49152]  = (__bf16)Wv[i - 49152];
  else if (i < 98304) wob[i - 81920]  = (__bf16)Wo[i - 81920];
  if (i < 128) bqs[i] = bq[i] * SCALE_L2E;
}

// Per-wave: write D[o][n] fragments transposed into a [16 n][128 o] bf16 LDS
// tile (XOR swizzled), then copy rows coalesced to dst.
template <bool SWZ>
__device__ __forceinline__ void store_tile_T(char* myt, const f32x4* acc, int g, int r,
                                             __bf16* dst_base) {
#pragma unroll
  for (int oc = 0; oc < 8; ++oc) {
#pragma unroll
    for (int rr = 0; rr < 4; ++rr) {
      int o = oc * 16 + g * 4 + rr;
      int byte = (r << 8) + (o << 1);
      byte ^= (r & 7) << 4;
      *(__bf16*)(myt + byte) = (__bf16)acc[oc][rr];
    }
  }
  int l = g * 16 + r;
#pragma unroll
  for (int p = 0; p < 4; ++p) {
    int u = p * 64 + l, row = u >> 4, seg = u & 15;
    int byte = (row << 8) + (seg << 4);
    if (!SWZ) byte ^= (row & 7) << 4;
    int4 v = *(int4*)(myt + byte);
    *(int4*)(dst_base + row * 128 + seg * 8) = v;
  }
}

// ---------------- K1: fused Q / K+V projections ----------------------------
// grid 512: bid<256 -> Q-part, else KV-part.
__global__ __launch_bounds__(256) void k_proj(const float* __restrict__ xq,
                                              const float* __restrict__ xkv,
                                              const __bf16* __restrict__ wqb,
                                              const __bf16* __restrict__ wkb,
                                              const __bf16* __restrict__ wvb,
                                              const float* __restrict__ bqs,
                                              const float* __restrict__ bk,
                                              const float* __restrict__ bv,
                                              __bf16* __restrict__ Qt,
                                              __bf16* __restrict__ Kt,
                                              __bf16* __restrict__ Vm) {
  const int t = threadIdx.x, w = t >> 6, l = t & 63, r = l & 15, g = l >> 4;
  __shared__ __align__(16) char lds[16384];
  char* myt = lds + (w << 12);

  if (blockIdx.x < 256) {
    const int b = blockIdx.x >> 6;
    const int n0 = (blockIdx.x & 63) << 6;
    const int nl = n0 + (w << 4) + r;
    const float* xb = xq + ((size_t)b << 19);
    bf16x8 bx[4];
#pragma unroll
    for (int cc = 0; cc < 4; ++cc) {
#pragma unroll
      for (int i = 0; i < 8; ++i) {
        int c = cc * 32 + g * 8 + i;
        bx[cc][i] = (__bf16)xb[c * 4096 + nl];
      }
    }
    f32x4 acc[8];
#pragma unroll
    for (int oc = 0; oc < 8; ++oc)
#pragma unroll
      for (int rr = 0; rr < 4; ++rr) acc[oc][rr] = bqs[oc * 16 + g * 4 + rr];
#pragma unroll
    for (int oc = 0; oc < 8; ++oc) {
#pragma unroll
      for (int cc = 0; cc < 4; ++cc) {
        bf16x8 a = ld_frag(wqb + (oc * 16 + r) * 128 + cc * 32 + g * 8);
        acc[oc] = MFMA16(a, bx[cc], acc[oc]);
      }
    }
    store_tile_T<false>(myt, acc, g, r, Qt + ((size_t)(b * NSP + n0 + w * 16)) * 128);
  } else {
    const int bid = blockIdx.x - 256;
    const int b = bid >> 6;
    const int n0 = (bid & 63) << 6;
    const int nl = n0 + (w << 4) + r;
    const float* xb = xkv + ((size_t)b << 20);
    bf16x8 bx[8];
#pragma unroll
    for (int cc = 0; cc < 8; ++cc) {
#pragma unroll
      for (int i = 0; i < 8; ++i) {
        int c = cc * 32 + g * 8 + i;
        bx[cc][i] = (__bf16)xb[(size_t)c * 4096 + nl];
      }
    }
    f32x4 acc[8];
#pragma unroll
    for (int oc = 0; oc < 8; ++oc)
#pragma unroll
      for (int rr = 0; rr < 4; ++rr) acc[oc][rr] = bk[oc * 16 + g * 4 + rr];
#pragma unroll
    for (int oc = 0; oc < 8; ++oc) {
#pragma unroll
      for (int cc = 0; cc < 8; ++cc) {
        bf16x8 a = ld_frag(wkb + (oc * 16 + r) * 256 + cc * 32 + g * 8);
        acc[oc] = MFMA16(a, bx[cc], acc[oc]);
      }
    }
    store_tile_T<true>(myt, acc, g, r, Kt + ((size_t)(b * NSP + n0 + w * 16)) * 128);

    f32x4 av[8];
#pragma unroll
    for (int oc = 0; oc < 8; ++oc)
#pragma unroll
      for (int rr = 0; rr < 4; ++rr) av[oc][rr] = bv[oc * 16 + g * 4 + rr];
#pragma unroll
    for (int oc = 0; oc < 8; ++oc) {
#pragma unroll
      for (int cc = 0; cc < 8; ++cc) {
        bf16x8 a = ld_frag(wvb + (oc * 16 + r) * 256 + cc * 32 + g * 8);
        av[oc] = MFMA16(a, bx[cc], av[oc]);
      }
    }
    // V stored [B][128][N], pre-swizzled: key n at n ^ ((ch&7)<<3)
#pragma unroll
    for (int oc = 0; oc < 8; ++oc) {
#pragma unroll
      for (int rr = 0; rr < 4; ++rr) {
        int o = oc * 16 + g * 4 + rr;
        Vm[((size_t)(b * 128 + o) << 12) + (nl ^ ((o & 7) << 3))] = (__bf16)av[oc][rr];
      }
    }
  }
}

// ---------------- K3: flash attention (swapped operands, 32 q-rows/wave) ---
// 4 waves/block (256 thr), 128 q-rows/block, LDS 80 KB -> 2 blocks/CU.
// grid = 4*SPLIT combos * 32 qtiles. Swapped QK^T: s = mfma(K,Q) -> lane holds
// S^T[keys][query=r]; softmax per-lane + 2 shfl. PV: acc = mfma(V^T,P^T).
template <int SPLIT>
__global__ __launch_bounds__(256, 2) void k_flash(const __bf16* __restrict__ Qt,
                                                  const __bf16* __restrict__ Kt,
                                                  const __bf16* __restrict__ Vm,
                                                  __bf16* __restrict__ Op,
                                                  float2* __restrict__ Ml) {
  const int bid = blockIdx.x;
  const int combo = bid & (4 * SPLIT - 1), qtile = bid / (4 * SPLIT);
  const int b = combo & 3, ks = combo >> 2;
  const int q0 = qtile << 7;
  const int NK = NSP / SPLIT;
  const int t = threadIdx.x, w = t >> 6, l = t & 63, r = l & 15, g = l >> 4;

  __shared__ __align__(16) char kl[2][16384];
  __shared__ __align__(16) char vl[2][16384];
  __shared__ __align__(16) char pl[4][4096];

  // Q fragments for two row-groups (queries q0+w*32+r and +16+r)
  bf16x8 aq0[4], aq1[4];
  {
    const __bf16* qp0 = Qt + ((size_t)(b * NSP + q0 + w * 32 + r)) * 128;
#pragma unroll
    for (int cc = 0; cc < 4; ++cc) {
      aq0[cc] = ld_frag(qp0 + cc * 32 + g * 8);
      aq1[cc] = ld_frag(qp0 + 16 * 128 + cc * 32 + g * 8);
    }
  }

  f32x4 acc0[8], acc1[8];
#pragma unroll
  for (int oc = 0; oc < 8; ++oc) {
    acc0[oc] = (f32x4){0.f, 0.f, 0.f, 0.f};
    acc1[oc] = (f32x4){0.f, 0.f, 0.f, 0.f};
  }
  float m0 = -1e30f, l0 = 0.f, m1 = -1e30f, l1 = 0.f;

  const char* kbase = (const char*)(Kt + ((size_t)(b * NSP) + ks * NK) * 128);
  const char* vbase = (const char*)(Vm + (size_t)b * 128 * NSP + ks * NK);

  auto STAGE = [&](int bi, int tt) {
#pragma unroll
    for (int i = 0; i < 4; ++i) {  // K: 16 KB (pre-swizzled rows)
      int c = i * 4 + w;
      load_lds16(kbase + tt * 16384 + c * 1024 + l * 16, &kl[bi][c * 1024]);
    }
#pragma unroll
    for (int i = 0; i < 4; ++i) {  // V: 128 ch rows x 128 B
      int c0 = (i * 4 + w) * 8;
      int ch = c0 + (l >> 3);
      load_lds16(vbase + (size_t)ch * 8192 + tt * 128 + (l & 7) * 16,
                 &vl[bi][c0 * 128]);
    }
  };

  STAGE(0, 0);
  __syncthreads();

  const int nit = NK / 64;
  for (int it = 0; it < nit; ++it) {
    const int cur = it & 1;
    if (it + 1 < nit) STAGE(cur ^ 1, it + 1);

    // ---- QK^T (swapped: A=K, B=Q). kf reused for both row-groups ----
    const char* kt = kl[cur];
    f32x4 s0[4], s1[4];
#pragma unroll
    for (int sg = 0; sg < 4; ++sg) {
      s0[sg] = (f32x4){0.f, 0.f, 0.f, 0.f};
      s1[sg] = (f32x4){0.f, 0.f, 0.f, 0.f};
    }
    __builtin_amdgcn_s_setprio(1);
#pragma unroll
    for (int cc = 0; cc < 4; ++cc) {
#pragma unroll
      for (int sg = 0; sg < 4; ++sg) {
        int addr = ((sg * 16 + r) << 8) + ((cc * 64 + (g << 4)) ^ ((r & 7) << 4));
        bf16x8 kf = ld_frag(kt + addr);
        s0[sg] = MFMA16(kf, aq0[cc], s0[sg]);
        s1[sg] = MFMA16(kf, aq1[cc], s1[sg]);
      }
    }
    __builtin_amdgcn_s_setprio(0);

    // ---- per-lane online softmax (lane = one query per set) ----
    float mx0 = s0[0][0], mx1 = s1[0][0];
#pragma unroll
    for (int sg = 0; sg < 4; ++sg)
#pragma unroll
      for (int rr = 0; rr < 4; ++rr) {
        mx0 = fmaxf(mx0, s0[sg][rr]);
        mx1 = fmaxf(mx1, s1[sg][rr]);
      }
    mx0 = fmaxf(mx0, __shfl_xor(mx0, 16));
    mx0 = fmaxf(mx0, __shfl_xor(mx0, 32));
    mx1 = fmaxf(mx1, __shfl_xor(mx1, 16));
    mx1 = fmaxf(mx1, __shfl_xor(mx1, 32));
    // defer-max: rescale only when a lane's max grew past threshold
    if (__any(fmaxf(mx0 - m0, mx1 - m1) > 8.f)) {
      float n0f = fmaxf(m0, mx0), n1f = fmaxf(m1, mx1);
      float a0 = exp2f(m0 - n0f), a1 = exp2f(m1 - n1f);
      m0 = n0f; m1 = n1f;
      l0 *= a0; l1 *= a1;
#pragma unroll
      for (int oc = 0; oc < 8; ++oc) {
#pragma unroll
        for (int rr = 0; rr < 4; ++rr) {
          acc0[oc][rr] *= a0;
          acc1[oc][rr] *= a1;
        }
      }
    }
    float rs0 = 0.f, rs1 = 0.f;
#pragma unroll
    for (int sg = 0; sg < 4; ++sg)
#pragma unroll
      for (int rr = 0; rr < 4; ++rr) {
        s0[sg][rr] = exp2f(s0[sg][rr] - m0);
        s1[sg][rr] = exp2f(s1[sg][rr] - m1);
        rs0 += s0[sg][rr];
        rs1 += s1[sg][rr];
      }
    rs0 += __shfl_xor(rs0, 16);
    rs0 += __shfl_xor(rs0, 32);
    rs1 += __shfl_xor(rs1, 16);
    rs1 += __shfl_xor(rs1, 32);
    l0 += rs0;
    l1 += rs1;

    // ---- P -> bf16, per-wave LDS transpose ([32 q][64 k], swizzled) ----
    char* ptl = pl[w];
#pragma unroll
    for (int sg = 0; sg < 4; ++sg) {
      uint2 v0, v1;
      v0.x = pk2(s0[sg][0], s0[sg][1]);
      v0.y = pk2(s0[sg][2], s0[sg][3]);
      v1.x = pk2(s1[sg][0], s1[sg][1]);
      v1.y = pk2(s1[sg][2], s1[sg][3]);
      int off = (sg * 32 + g * 8) ^ ((r & 7) << 4);
      *(uint2*)(ptl + (r << 7) + off) = v0;
      *(uint2*)(ptl + ((16 + r) << 7) + off) = v1;
    }
    bf16x8 pb0[2], pb1[2];
#pragma unroll
    for (int kk = 0; kk < 2; ++kk) {
      int off = (kk * 64 + (g << 4)) ^ ((r & 7) << 4);
      pb0[kk] = ld_frag(ptl + (r << 7) + off);
      pb1[kk] = ld_frag(ptl + ((16 + r) << 7) + off);
    }

    // ---- PV (swapped: A=V^T, B=P^T). vf reused for both row-groups ----
    const char* vt = vl[cur];
    __builtin_amdgcn_s_setprio(1);
#pragma unroll
    for (int kk = 0; kk < 2; ++kk) {
#pragma unroll
      for (int oc = 0; oc < 8; ++oc) {
        int addr = ((oc * 16 + r) << 7) + ((kk * 64 + (g << 4)) ^ ((r & 7) << 4));
        bf16x8 vf = ld_frag(vt + addr);
        acc0[oc] = MFMA16(vf, pb0[kk], acc0[oc]);
        acc1[oc] = MFMA16(vf, pb1[kk], acc1[oc]);
      }
    }
    __builtin_amdgcn_s_setprio(0);
    __syncthreads();
  }

  // ---- partial store: lane holds O^T[ch=oc*16+4g+rr][q] for q=r / 16+r ----
  const size_t prow = (size_t)((ks * 4 + b) * NSP + q0 + w * 32 + r) * 128;
  __bf16* op0 = Op + prow;
  __bf16* op1 = Op + prow + 16 * 128;
#pragma unroll
  for (int oc = 0; oc < 8; ++oc) {
    uint2 v0, v1;
    v0.x = pk2(acc0[oc][0], acc0[oc][1]);
    v0.y = pk2(acc0[oc][2], acc0[oc][3]);
    v1.x = pk2(acc1[oc][0], acc1[oc][1]);
    v1.y = pk2(acc1[oc][2], acc1[oc][3]);
    *(uint2*)(op0 + oc * 16 + 4 * g) = v0;
    *(uint2*)(op1 + oc * 16 + 4 * g) = v1;
  }
  if (g == 0) {
    size_t mlrow = (size_t)(ks * 4 + b) * NSP + q0 + w * 32 + r;
    Ml[mlrow] = make_float2(m0, l0);
    Ml[mlrow + 16] = make_float2(m1, l1);
  }
}

// ---------------- K4: combine splits + out projection + residual -----------
template <int SPLIT>
__global__ __launch_bounds__(256) void k_oproj(const __bf16* __restrict__ Op,
                                               const float2* __restrict__ Ml,
                                               const __bf16* __restrict__ wob,
                                               const float* __restrict__ bo,
                                               const float* __restrict__ xq,
                                               float* __restrict__ out) {
  const int b = blockIdx.x >> 6;
  const int n0 = (blockIdx.x & 63) << 6;
  const int t = threadIdx.x, w = t >> 6, l = t & 63, r = l & 15, g = l >> 4;
  const int nl = n0 + (w << 4) + r;

  float2 e[SPLIT];
  float M = -1e30f;
#pragma unroll
  for (int s = 0; s < SPLIT; ++s) {
    e[s] = Ml[(size_t)(s * 4 + b) * NSP + nl];
    M = fmaxf(M, e[s].x);
  }
  float wk[SPLIT], den = 0.f;
#pragma unroll
  for (int s = 0; s < SPLIT; ++s) {
    wk[s] = exp2f(e[s].x - M);
    den += e[s].y * wk[s];
  }
  float inv = 1.f / den;
#pragma unroll
  for (int s = 0; s < SPLIT; ++s) wk[s] *= inv;

  bf16x8 bfr[4];
#pragma unroll
  for (int cc = 0; cc < 4; ++cc) {
    float a8[8];
#pragma unroll
    for (int j = 0; j < 8; ++j) a8[j] = 0.f;
#pragma unroll
    for (int s = 0; s < SPLIT; ++s) {
      bf16x8 a = ld_frag(Op + ((size_t)(s * 4 + b) * NSP + nl) * 128 + cc * 32 + g * 8);
#pragma unroll
      for (int j = 0; j < 8; ++j) a8[j] += (float)a[j] * wk[s];
    }
#pragma unroll
    for (int j = 0; j < 8; ++j) bfr[cc][j] = (__bf16)a8[j];
  }

  f32x4 acc[8];
#pragma unroll
  for (int oc = 0; oc < 8; ++oc)
#pragma unroll
    for (int rr = 0; rr < 4; ++rr) acc[oc][rr] = bo[oc * 16 + g * 4 + rr];
#pragma unroll
  for (int oc = 0; oc < 8; ++oc) {
#pragma unroll
    for (int cc = 0; cc < 4; ++cc) {
      bf16x8 a = ld_frag(wob + (oc * 16 + r) * 128 + cc * 32 + g * 8);
      acc[oc] = MFMA16(a, bfr[cc], acc[oc]);
    }
  }
#pragma unroll
  for (int oc = 0; oc < 8; ++oc) {
#pragma unroll
    for (int rr = 0; rr < 4; ++rr) {
      int o = oc * 16 + g * 4 + rr;
      size_t idx = ((size_t)(b * 128 + o) << 12) + nl;
      out[idx] = acc[oc][rr] + xq[idx];
    }
  }
}

extern "C" void kernel_launch(void* const* d_in, const int* in_sizes, int n_in,
                              void* d_out, int out_size, void* d_ws, size_t ws_size,
                              hipStream_t stream) {
  const float* xq = (const float*)d_in[0];
  const float* xkv = (const float*)d_in[1];
  const float* Wq = (const float*)d_in[2];
  const float* bq = (const float*)d_in[3];
  const float* Wk = (const float*)d_in[4];
  const float* bk = (const float*)d_in[5];
  const float* Wv = (const float*)d_in[6];
  const float* bv = (const float*)d_in[7];
  const float* Wo = (const float*)d_in[8];
  const float* bo = (const float*)d_in[9];
  float* out = (float*)d_out;

  char* ws = (char*)d_ws;
  __bf16* wqb = (__bf16*)(ws);
  __bf16* wkb = (__bf16*)(ws + 32768);
  __bf16* wvb = (__bf16*)(ws + 98304);
  __bf16* wob = (__bf16*)(ws + 163840);
  float* bqs = (float*)(ws + 196608);
  __bf16* Qt = (__bf16*)(ws + 197120);
  __bf16* Kt = (__bf16*)(ws + 197120 + 4194304);
  __bf16* Vm = (__bf16*)(ws + 197120 + 2 * 4194304);
  __bf16* Op = (__bf16*)(ws + 197120 + 3 * 4194304);
  float2* Ml = (float2*)(ws + 197120 + 3 * 4194304 + 16777216);

  k_prep<<<dim3(384), dim3(256), 0, stream>>>(Wq, bq, Wk, Wv, Wo, wqb, wkb, wvb, wob, bqs);
  k_proj<<<dim3(512), dim3(256), 0, stream>>>(xq, xkv, wqb, wkb, wvb, bqs, bk, bv,
                                              Qt, Kt, Vm);

  const size_t need4 = 197120ull + 3ull * 4194304 + 16777216 + 524288;
  if (ws_size >= need4) {
    k_flash<4><<<dim3(512), dim3(256), 0, stream>>>(Qt, Kt, Vm, Op, Ml);
    k_oproj<4><<<dim3(256), dim3(256), 0, stream>>>(Op, Ml, wob, bo, xq, out);
  } else {
    k_flash<2><<<dim3(256), dim3(256), 0, stream>>>(Qt, Kt, Vm, Op, Ml);
    k_oproj<2><<<dim3(256), dim3(256), 0, stream>>>(Op, Ml, wob, bo, xq, out);
  }
}